// Round 6
// baseline (464.560 us; speedup 1.0000x reference)
//
#include <hip/hip_runtime.h>
#include <math.h>

#define NN 100000     // nodes
#define NE 1600000    // edges
#define D  128        // feature dim
#define NW 64         // u32 words per row (D/2 packed bf16x2)
#define NL 3          // layers

typedef unsigned int u32;
typedef __attribute__((ext_vector_type(8))) short bf16x8;
typedef __attribute__((ext_vector_type(4))) float f32x4;

// ---- packed bf16x2 helpers (RNE) ----
__device__ inline float blo(u32 v) { return __uint_as_float(v << 16); }
__device__ inline float bhi(u32 v) { return __uint_as_float(v & 0xffff0000u); }
__device__ inline u32 bpack(float x, float y) {
  u32 xb = __float_as_uint(x), yb = __float_as_uint(y);
  xb = (xb + 0x7fffu + ((xb >> 16) & 1u)) >> 16;
  yb = (yb + 0x7fffu + ((yb >> 16) & 1u)) & 0xffff0000u;
  return xb | yb;
}

// ---------------- degree count: 8 edges/thread, fire-and-forget atomics ------

__global__ __launch_bounds__(256) void k_count(const int* __restrict__ dstv,
                                               unsigned* __restrict__ deg) {
  const int base = (blockIdx.x * 256 + threadIdx.x) * 8;
  if (base + 8 <= NE) {
    const int4 d0 = *(const int4*)(dstv + base);
    const int4 d1 = *(const int4*)(dstv + base + 4);
    atomicAdd(&deg[d0.x], 1u); atomicAdd(&deg[d0.y], 1u);
    atomicAdd(&deg[d0.z], 1u); atomicAdd(&deg[d0.w], 1u);
    atomicAdd(&deg[d1.x], 1u); atomicAdd(&deg[d1.y], 1u);
    atomicAdd(&deg[d1.z], 1u); atomicAdd(&deg[d1.w], 1u);
  } else {
    for (int i = base; i < NE; ++i) atomicAdd(&deg[dstv[i]], 1u);
  }
}

__global__ __launch_bounds__(256) void k_dinv(const unsigned* __restrict__ deg,
                                              float* __restrict__ dinv) {
  int i = blockIdx.x * 256 + threadIdx.x;
  if (i < NN) dinv[i] = 1.0f / sqrtf((float)(deg[i] + 1u));
}

// ---------------- x -> packed bf16 ----------------

__global__ __launch_bounds__(256) void k_cvt(const float* __restrict__ x,
                                             u32* __restrict__ xb) {
  int i = blockIdx.x * 256 + threadIdx.x;
  if (i < NN * NW) {
    const float2 v = *(const float2*)&x[(size_t)i * 2];
    xb[i] = bpack(v.x, v.y);
  }
}

// ---------------- W (f32 [k][n]) -> bf16 W^T [n][k], packed u32 ----------------

__global__ __launch_bounds__(256) void k_wcvt(const float* __restrict__ Ws,
                                              u32* __restrict__ Wtb) {
  int i = blockIdx.x * 256 + threadIdx.x;   // l*8192 + n*64 + kw
  if (i >= NL * 128 * 64) return;
  const int l = i >> 13, rem = i & 8191, n = rem >> 6, kw = rem & 63;
  const float* Wp = Ws + l * (D * D);
  Wtb[i] = bpack(Wp[(2 * kw) * D + n], Wp[(2 * kw + 1) * D + n]);
}

// ---------------- CSR build: 3-stage exclusive scan ----------------

__global__ __launch_bounds__(256) void k_scan1(const unsigned* __restrict__ deg,
                                               unsigned* __restrict__ bsum) {
  __shared__ unsigned s[256];
  int t = threadIdx.x;
  int i = blockIdx.x * 256 + t;
  s[t] = (i < NN) ? deg[i] : 0u;
  __syncthreads();
  for (int off = 128; off > 0; off >>= 1) {
    if (t < off) s[t] += s[t + off];
    __syncthreads();
  }
  if (t == 0) bsum[blockIdx.x] = s[0];
}

__global__ __launch_bounds__(512) void k_scan2(const unsigned* __restrict__ bsum,
                                               unsigned* __restrict__ boff, int nb) {
  __shared__ unsigned s[512];
  int t = threadIdx.x;
  unsigned v = (t < nb) ? bsum[t] : 0u;
  s[t] = v;
  __syncthreads();
  for (int off = 1; off < 512; off <<= 1) {
    unsigned x = (t >= off) ? s[t - off] : 0u;
    __syncthreads();
    s[t] += x;
    __syncthreads();
  }
  if (t < nb) boff[t] = s[t] - v;   // exclusive
}

// scan3 also seeds fillcnt = rowptr so k_fill's atomic needs no rowptr load.
__global__ __launch_bounds__(256) void k_scan3(const unsigned* __restrict__ deg,
                                               const unsigned* __restrict__ boff,
                                               unsigned* __restrict__ rowptr,
                                               unsigned* __restrict__ fillcnt) {
  __shared__ unsigned s[256];
  int t = threadIdx.x;
  int i = blockIdx.x * 256 + t;
  unsigned v = (i < NN) ? deg[i] : 0u;
  s[t] = v;
  __syncthreads();
  for (int off = 1; off < 256; off <<= 1) {
    unsigned x = (t >= off) ? s[t - off] : 0u;
    __syncthreads();
    s[t] += x;
    __syncthreads();
  }
  unsigned excl = s[t] - v + boff[blockIdx.x];
  if (i <= NN) rowptr[i] = excl;    // i==NN lands exactly on total == NE
  if (i < NN)  fillcnt[i] = excl;
}

// ---------------- CSR fill: 8 edges/thread, 8 atomic chains in flight --------

__global__ __launch_bounds__(256) void k_fill(const int* __restrict__ srcv,
                                              const int* __restrict__ dstv,
                                              const float* __restrict__ dinv,
                                              unsigned* __restrict__ fillcnt,  // = rowptr seed
                                              uint2* __restrict__ edat) {
  const int base = (blockIdx.x * 256 + threadIdx.x) * 8;
  if (base + 8 <= NE) {
    const int4 d0 = *(const int4*)(dstv + base);
    const int4 d1 = *(const int4*)(dstv + base + 4);
    const int4 s0 = *(const int4*)(srcv + base);
    const int4 s1 = *(const int4*)(srcv + base + 4);
    const int ds[8] = {d0.x, d0.y, d0.z, d0.w, d1.x, d1.y, d1.z, d1.w};
    const int ss[8] = {s0.x, s0.y, s0.z, s0.w, s1.x, s1.y, s1.z, s1.w};
    unsigned pos[8];
    float nd[8], ns[8];
#pragma unroll
    for (int q = 0; q < 8; ++q) pos[q] = atomicAdd(&fillcnt[ds[q]], 1u);
#pragma unroll
    for (int q = 0; q < 8; ++q) { nd[q] = dinv[ds[q]]; ns[q] = dinv[ss[q]]; }
#pragma unroll
    for (int q = 0; q < 8; ++q) {
      uint2 v; v.x = (u32)ss[q]; v.y = __float_as_uint(ns[q] * nd[q]);
      edat[pos[q]] = v;
    }
  } else {
    for (int i = base; i < NE; ++i) {
      const int d = dstv[i], s = srcv[i];
      const unsigned pos = atomicAdd(&fillcnt[d], 1u);
      uint2 v; v.x = (u32)s; v.y = __float_as_uint(dinv[s] * dinv[d]);
      edat[pos] = v;
    }
  }
}

// ---------------- GEMM: hw = h @ W  (bf16 MFMA, W^T in swizzled LDS) ----------
// 512 threads (8 waves), 128 rows/block. Per wave: 16 rows x 128 cols via
// 32x mfma_f32_16x16x32_bf16. A frag: row=lane&15, k=(lane>>4)*8+j (m89/m91
// layout). B frag from LDS W^T[n][k], XOR-swizzled (byte ^= (n&7)<<4) on both
// write and read (rule #21). D: col=lane&15, row=(lane>>4)*4+reg. Epilogue
// packs col pairs via shfl_xor(1) into bf16x2 words.

__global__ __launch_bounds__(512, 4) void k_gemm(const u32* __restrict__ Ab,
                                                 const u32* __restrict__ Wtb,
                                                 u32* __restrict__ Bb) {
  __shared__ u32 Wl[128 * 64];   // 32 KB
  const int t = threadIdx.x;
#pragma unroll
  for (int i = 0; i < 4; ++i) {
    const int idx = (t + i * 512) * 4;          // u32 index of a 16B chunk
    const uint4 v = *(const uint4*)(Wtb + idx);
    const int byte = idx * 4;
    const int sw = byte ^ (((byte >> 8) & 7) << 4);
    *(uint4*)((char*)Wl + sw) = v;
  }
  __syncthreads();

  const int wave = t >> 6, lane = t & 63;
  const int hi = lane >> 4;                     // 0..3
  const int lo = lane & 15;
  int row = blockIdx.x * 128 + wave * 16 + lo;
  const int rowc = row < NN ? row : NN - 1;     // clamp reads, guard writes

  bf16x8 af[4];
#pragma unroll
  for (int ks = 0; ks < 4; ++ks)
    af[ks] = *(const bf16x8*)(Ab + (size_t)rowc * NW + ks * 16 + hi * 4);

  f32x4 acc[8];
#pragma unroll
  for (int ct = 0; ct < 8; ++ct) acc[ct] = (f32x4){0.f, 0.f, 0.f, 0.f};

#pragma unroll
  for (int ks = 0; ks < 4; ++ks) {
#pragma unroll
    for (int ct = 0; ct < 8; ++ct) {
      const int n = ct * 16 + lo;
      const int addr = (n * 256 + ks * 64 + hi * 16) ^ ((n & 7) << 4);
      const bf16x8 bf = *(const bf16x8*)((const char*)Wl + addr);
      acc[ct] = __builtin_amdgcn_mfma_f32_16x16x32_bf16(af[ks], bf, acc[ct], 0, 0, 0);
    }
  }

  const int rbase = blockIdx.x * 128 + wave * 16 + hi * 4;
  const bool even = (lane & 1) == 0;
  const int wcol = lo >> 1;                     // word index within ct's 8
#pragma unroll
  for (int ct = 0; ct < 8; ++ct) {
    float p0 = __shfl_xor(acc[ct][0], 1, 64);
    float p1 = __shfl_xor(acc[ct][1], 1, 64);
    float p2 = __shfl_xor(acc[ct][2], 1, 64);
    float p3 = __shfl_xor(acc[ct][3], 1, 64);
    const u32 wA = even ? bpack(acc[ct][0], p0) : bpack(p2, acc[ct][2]);
    const u32 wB = even ? bpack(acc[ct][1], p1) : bpack(p3, acc[ct][3]);
    const int rA = rbase + (even ? 0 : 2);
    if (rA < NN)     Bb[(size_t)rA * NW + ct * 8 + wcol] = wA;
    if (rA + 1 < NN) Bb[(size_t)(rA + 1) * NW + ct * 8 + wcol] = wB;
  }
}

// ---------------- Aggregation: one wave per node, bf16 gather, fused bias+ReLU ----

__global__ __launch_bounds__(256) void k_agg(const u32* __restrict__ hwb,
                                             const uint2* __restrict__ edat,
                                             const unsigned* __restrict__ rowptr,
                                             const float* __restrict__ dinv,
                                             const float* __restrict__ bias,
                                             u32* __restrict__ hob) {
  const int widt = (blockIdx.x * 256 + threadIdx.x) >> 6;
  if (widt >= NN) return;
  const int wid = __builtin_amdgcn_readfirstlane(widt);
  const int lane = threadIdx.x & 63;

  const float di = dinv[wid];
  const float sn = di * di;
  const u32 sv = hwb[(size_t)wid * NW + lane];
  float ax = blo(sv) * sn, ay = bhi(sv) * sn;

  const unsigned s = rowptr[wid], e = rowptr[wid + 1];
  unsigned j = s;
  for (; j + 8 <= e; j += 8) {
    uint2 ed[8];
    u32 u[8];
#pragma unroll
    for (int q = 0; q < 8; ++q) ed[q] = edat[j + q];
#pragma unroll
    for (int q = 0; q < 8; ++q) u[q] = hwb[(size_t)ed[q].x * NW + lane];
#pragma unroll
    for (int q = 0; q < 8; ++q) {
      const float w = __uint_as_float(ed[q].y);
      ax = fmaf(w, blo(u[q]), ax); ay = fmaf(w, bhi(u[q]), ay);
    }
  }
  for (; j + 4 <= e; j += 4) {
    uint2 ed[4];
    u32 u[4];
#pragma unroll
    for (int q = 0; q < 4; ++q) ed[q] = edat[j + q];
#pragma unroll
    for (int q = 0; q < 4; ++q) u[q] = hwb[(size_t)ed[q].x * NW + lane];
#pragma unroll
    for (int q = 0; q < 4; ++q) {
      const float w = __uint_as_float(ed[q].y);
      ax = fmaf(w, blo(u[q]), ax); ay = fmaf(w, bhi(u[q]), ay);
    }
  }
  for (; j < e; ++j) {
    const uint2 ed = edat[j];
    const u32 u = hwb[(size_t)ed.x * NW + lane];
    const float w = __uint_as_float(ed.y);
    ax = fmaf(w, blo(u), ax); ay = fmaf(w, bhi(u), ay);
  }

  const float2 b = *(const float2*)&bias[lane * 2];
  ax += b.x; ay += b.y;
  ax = ax > 0.f ? ax : 0.f;
  ay = ay > 0.f ? ay : 0.f;
  hob[(size_t)wid * NW + lane] = bpack(ax, ay);
}

// ---------------- Head GEMV: out = h @ head_W + head_b ----------------

__global__ __launch_bounds__(256) void k_head(const u32* __restrict__ hb,
                                              const float* __restrict__ hW,
                                              const float* __restrict__ hbv,
                                              float* __restrict__ out) {
  const int widt = (blockIdx.x * 256 + threadIdx.x) >> 6;
  if (widt >= NN) return;
  const int wid = __builtin_amdgcn_readfirstlane(widt);
  const int lane = threadIdx.x & 63;
  const u32 v = hb[(size_t)wid * NW + lane];
  const float2 w = *(const float2*)&hW[lane * 2];
  float sum = blo(v) * w.x + bhi(v) * w.y;
#pragma unroll
  for (int off = 32; off > 0; off >>= 1) sum += __shfl_down(sum, off, 64);
  if (lane == 0) out[wid] = sum + hbv[0];
}

// ---------------- launch ----------------

extern "C" void kernel_launch(void* const* d_in, const int* in_sizes, int n_in,
                              void* d_out, int out_size, void* d_ws, size_t ws_size,
                              hipStream_t stream) {
  const float* x   = (const float*)d_in[0];
  const int*   ei  = (const int*)d_in[1];
  const float* Ws  = (const float*)d_in[2];
  const float* bs  = (const float*)d_in[3];
  const float* hW  = (const float*)d_in[4];
  const float* hb  = (const float*)d_in[5];
  float* out = (float*)d_out;

  char* w = (char*)d_ws;
  u32*      bufA    = (u32*)w;      w += (size_t)NN * NW * 4;      // 25.6 MB (h)
  u32*      bufB    = (u32*)w;      w += (size_t)NN * NW * 4;      // 25.6 MB (hw)
  uint2*    edat    = (uint2*)w;    w += (size_t)NE * 8;           // 12.8 MB
  u32*      Wtb     = (u32*)w;      w += (size_t)NL * 128 * 64 * 4; // 96 KB
  unsigned* rowptr  = (unsigned*)w; w += (size_t)(NN + 16) * 4;
  unsigned* deg     = (unsigned*)w; w += (size_t)NN * 4;
  unsigned* fillcnt = (unsigned*)w; w += (size_t)NN * 4;
  float*    dinv    = (float*)w;    w += (size_t)NN * 4;
  unsigned* bsum    = (unsigned*)w; w += 512 * 4;
  unsigned* boff    = (unsigned*)w; w += 512 * 4;

  const int* srcv = ei;
  const int* dstv = ei + NE;

  hipMemsetAsync(deg, 0, (size_t)NN * 4, stream);

  const int NB = (NN + 255) / 256;          // 391
  const int NB8 = (NE / 8 + 255) / 256;     // 782

  k_count<<<NB8, 256, 0, stream>>>(dstv, deg);
  k_dinv <<<NB, 256, 0, stream>>>(deg, dinv);
  k_cvt  <<<(NN * NW + 255) / 256, 256, 0, stream>>>(x, bufA);
  k_wcvt <<<(NL * 128 * 64 + 255) / 256, 256, 0, stream>>>(Ws, Wtb);
  k_scan1<<<NB, 256, 0, stream>>>(deg, bsum);
  k_scan2<<<1, 512, 0, stream>>>(bsum, boff, NB);
  k_scan3<<<NB, 256, 0, stream>>>(deg, boff, rowptr, fillcnt);
  k_fill <<<NB8, 256, 0, stream>>>(srcv, dstv, dinv, fillcnt, edat);

  for (int l = 0; l < NL; ++l) {
    k_gemm<<<(NN + 127) / 128, 512, 0, stream>>>(bufA, Wtb + (size_t)l * 128 * 64, bufB);
    k_agg <<<(NN + 3) / 4, 256, 0, stream>>>(bufB, edat, rowptr, dinv,
                                             bs + (size_t)l * D, bufA);
  }

  k_head<<<(NN + 3) / 4, 256, 0, stream>>>(bufA, hW, hb, out);
}